// Round 15
// baseline (631.694 us; speedup 1.0000x reference)
//
#include <hip/hip_runtime.h>
#include <hip/hip_bf16.h>
#include <stdint.h>
#include <stddef.h>

// RNN_arch_2_final: 3-cell stacked RNN, T=16, B=16384, hidden 256.
// R15 = R14 + (a) h3-recurrent GEMM moved into the B region (reads only OLD
// h3s; acc3 carried B->C'); C' = ab-part only, h3-write needs no internal
// barrier -> 6 barriers/step (was 7), B region gets 2 independent MFMA
// streams; (b) f2bf via __float2bfloat16 cast (compiler emits cvt_pk pairs;
// m240: don't hand-write the asm); (c) tanh = 1-2*rcp(e+1), upper-clamp only.

#define BN 16384
#define TT 16

typedef short s16x8 __attribute__((ext_vector_type(8)));
typedef short s16x4 __attribute__((ext_vector_type(4)));
typedef float f32x4 __attribute__((ext_vector_type(4)));

#define MFMA(a, b, c) __builtin_amdgcn_mfma_f32_16x16x32_bf16((a), (b), (c), 0, 0, 0)
// LDS-ordering barrier WITHOUT vmcnt drain (loop-top, D->E only).
#define BARL() asm volatile("s_waitcnt lgkmcnt(0)\n\ts_barrier" ::: "memory")

__device__ __forceinline__ short f2bf(float f) {
  __hip_bfloat16 h = __float2bfloat16(f);
  short s;
  __builtin_memcpy(&s, &h, 2);
  return s;
}
__device__ __forceinline__ float bf2f(short s) {
  union { uint32_t u; float f; } v; v.u = ((uint32_t)(uint16_t)s) << 16;
  return v.f;
}
__device__ __forceinline__ float fast_tanh(float x) {
  float e = __expf(2.f * fminf(x, 8.f));   // exp(-big)->0 is benign: gives -1
  return 1.f - 2.f * __builtin_amdgcn_rcpf(e + 1.f);
}
__device__ __forceinline__ void nt_st4(float* p, f32x4 v) {
  __builtin_nontemporal_store(v, (f32x4*)p);
}
__device__ __forceinline__ f32x4 nt_ld4(const float* p) {
  return __builtin_nontemporal_load((const f32x4*)p);
}
__device__ __forceinline__ s16x4 tanh4bf(f32x4 a) {
  return (s16x4){f2bf(fast_tanh(a[0])), f2bf(fast_tanh(a[1])),
                 f2bf(fast_tanh(a[2])), f2bf(fast_tanh(a[3]))};
}

struct PrepPtrs {
  const float *w1i, *w1h, *w1o, *w2i, *w2h, *w2o, *w3i, *w3h, *w3o;
  const float *b1i, *b1h, *b2i, *b2h, *b3i, *b3h, *bo1, *bo2, *bo3, *wfc, *bfc;
};

// Pack W[n][k] fragments: frag(kt,nt): elem(lane,e) = W[nt*16+(lane&15)][kt*32+(lane>>4)*8+e]
__global__ void prep_kernel(PrepPtrs pp, short* __restrict__ wpk, float* __restrict__ wmisc) {
  const float* P[9] = {pp.w1i, pp.w1h, pp.w1o, pp.w2i, pp.w2h, pp.w2o, pp.w3i, pp.w3h, pp.w3o};
  const int LD_[9] = {64, 256, 256, 64, 256, 256, 130, 256, 256};
  const int C0_[9] = {0, 0, 0, 0, 0, 0, 2, 0, 0};
  const int NT_[9] = {16, 16, 4, 16, 16, 4, 16, 16, 4};
  const int DO_[10] = {0, 16384, 81920, 98304, 114688, 180224, 196608, 229376, 294912, 311296};
  int stride = gridDim.x * blockDim.x;
  for (int g = blockIdx.x * blockDim.x + threadIdx.x; g < 311296; g += stride) {
    int m = 0;
    while (g >= DO_[m + 1]) ++m;
    int p = g - DO_[m];
    int NT = NT_[m];
    int frag = p >> 9, lane = (p >> 3) & 63, e = p & 7;
    int kt = frag / NT, nt = frag - kt * NT;
    int row = nt * 16 + (lane & 15);
    int col = kt * 32 + ((lane >> 4) << 3) + e;
    wpk[g] = f2bf(P[m][(size_t)row * LD_[m] + C0_[m] + col]);
  }
  for (int i = blockIdx.x * blockDim.x + threadIdx.x; i < 1602; i += stride) {
    float v;
    if      (i < 256)  v = pp.b1i[i]         + pp.b1h[i];
    else if (i < 512)  v = pp.b2i[i - 256]   + pp.b2h[i - 256];
    else if (i < 768)  v = pp.b3i[i - 512]   + pp.b3h[i - 512];
    else if (i < 832)  v = pp.bo1[i - 768];
    else if (i < 896)  v = pp.bo2[i - 832];
    else if (i < 960)  v = pp.bo3[i - 896];
    else if (i < 1088) v = pp.wfc[i - 960];
    else if (i < 1090) v = pp.bfc[i - 1088];
    else if (i < 1346) v = pp.w3i[(size_t)(i - 1090) * 130];
    else               v = pp.w3i[(size_t)(i - 1346) * 130 + 1];
    wmisc[i] = v;
  }
}

__launch_bounds__(512, 2)
__global__ void rnn_main(const float* __restrict__ x, const float* __restrict__ cue,
                         const float* __restrict__ hc1, const float* __restrict__ hc2,
                         const float* __restrict__ hc3, const float* __restrict__ hc4,
                         const short* __restrict__ wpk, const float* __restrict__ wmisc,
                         float* __restrict__ out) {
  // LDS pool. h tiles: element (r,c) at [r*256 + (c ^ ((r&7)<<3))].
  // Union (o12s+ofl | hscr): hscr live A1-epi..A2-epi; loop-top BARL fences.
  __shared__ __align__(16) char pool[141312];
  short* h1s  = (short*)pool;                    // 32768 B
  short* h2s  = (short*)(pool + 32768);          // 32768 B
  short* h3s  = (short*)(pool + 65536);          // 32768 B
  short* o12s = (short*)(pool + 98304);          // 16384 B  (union w/ hscr)
  float* ofl  = (float*)(pool + 114688);         // 18432 B  (union w/ hscr tail)
  short* hscr = (short*)(pool + 98304);          // 32768 B  scratch for h1new
  short* xls  = (short*)(pool + 133120);         // 8192 B   x tile (bf16, swz)
  __shared__ float cue0[64], cue1[64];
  __shared__ __align__(16) float misc[1604];

  const int tid = threadIdx.x;
  const int wv = tid >> 6;          // 0..7
  const int lane = tid & 63;
  const int lr = lane & 15;
  const int lq = lane >> 4;
  const int swz = (lr & 7) << 3;
  const int r0 = blockIdx.x * 64;

  float* out_ys  = out;
  float* out_h1  = out + 524288;
  float* out_h2  = out + 4718592;
  float* out_h3  = out + 8912896;
  float* out_h4  = out + 13107200;
  float* out_o1s = out + 17301504;
  float* out_o2s = out + 34078720;
  float* out_cue = out + 50855936;
  float* out_f1  = out + 51380224;
  float* out_f2  = out + 118489088;
  float* out_of  = out + 185597952;

  for (int i = tid; i < 1602; i += 512) misc[i] = wmisc[i];
  if (tid < 64) {
    float cv = cue[r0 + tid];
    cue0[tid] = cv * 10.f;
    cue1[tid] = 10.f * fabsf(cv - 1.f);
  }
  // stage initial h (f32 -> bf16, swizzled) + h4 passthrough
  for (int i = tid; i < 4096; i += 512) {
    int r = i >> 6, c0 = (i & 63) << 2;
    int li = r * 256 + (c0 ^ ((r & 7) << 3));
    size_t g = (size_t)(r0 + r) * 256 + c0;
    f32x4 v1 = __builtin_nontemporal_load((const f32x4*)(hc1 + g));
    f32x4 v2 = __builtin_nontemporal_load((const f32x4*)(hc2 + g));
    f32x4 v3 = __builtin_nontemporal_load((const f32x4*)(hc3 + g));
    f32x4 v4 = __builtin_nontemporal_load((const f32x4*)(hc4 + g));
    *(s16x4*)&h1s[li] = (s16x4){f2bf(v1[0]), f2bf(v1[1]), f2bf(v1[2]), f2bf(v1[3])};
    *(s16x4*)&h2s[li] = (s16x4){f2bf(v2[0]), f2bf(v2[1]), f2bf(v2[2]), f2bf(v2[3])};
    *(s16x4*)&h3s[li] = (s16x4){f2bf(v3[0]), f2bf(v3[1]), f2bf(v3[2]), f2bf(v3[3])};
    nt_st4(out_h4 + g, v4);
  }
  // stage x(t=0) into xls (prologue)
  const int xr = tid >> 3, xcq = (tid & 7) << 3;
  {
    const float* px = x + ((size_t)(r0 + xr)) * 64 + xcq;
    f32x4 a0 = nt_ld4(px);
    f32x4 a1 = nt_ld4(px + 4);
    *(s16x8*)&xls[xr * 64 + (xcq ^ ((xr & 7) << 3))] =
        (s16x8){f2bf(a0[0]), f2bf(a0[1]), f2bf(a0[2]), f2bf(a0[3]),
                f2bf(a1[0]), f2bf(a1[1]), f2bf(a1[2]), f2bf(a1[3])};
  }
  __syncthreads();

  const short* Wp1i  = wpk;
  const short* Wp1h  = wpk + 16384;
  const short* Wp1o  = wpk + 81920;
  const short* Wp2i  = wpk + 98304;
  const short* Wp2h  = wpk + 114688;
  const short* Wp2o  = wpk + 180224;
  const short* Wp3ab = wpk + 196608;
  const short* Wp3h  = wpk + 229376;
  const short* Wp3o  = wpk + 294912;
  const float* bh1v = misc;
  const float* bh2v = misc + 256;
  const float* bh3v = misc + 512;
  const float* bo1v = misc + 768;
  const float* bo2v = misc + 832;
  const float* bofv = misc + 896;
  const float* wfcv = misc + 960;
  const float* bfcv = misc + 1088;
  const float* w3c0 = misc + 1090;
  const float* w3c1 = misc + 1346;

  for (int t = 0; t < TT; ++t) {
    BARL();   // loop-top: LDS-only hazard fence (E(t-1) vs A1 hscr / xls)

    // ---------- Phase A1: cell 1 only (acc1 = 32 VGPRs live)
    {
      f32x4 acc1[4][2];
      #pragma unroll
      for (int j = 0; j < 2; ++j) {
        int nb = (2 * wv + j) * 16 + lq * 4;
        f32x4 b1 = *(const f32x4*)(bh1v + nb);
        #pragma unroll
        for (int rt = 0; rt < 4; ++rt) acc1[rt][j] = b1;
      }
      #pragma unroll
      for (int kt = 0; kt < 2; ++kt) {   // x part, K=64 (from LDS)
        s16x8 aw0 = *(const s16x8*)(Wp1i + ((size_t)(kt * 16 + 2 * wv) * 64 + lane) * 8);
        s16x8 aw1 = *(const s16x8*)(Wp1i + ((size_t)(kt * 16 + 2 * wv + 1) * 64 + lane) * 8);
        #pragma unroll
        for (int rt = 0; rt < 4; ++rt) {
          s16x8 xb = *(const s16x8*)&xls[(rt * 16 + lr) * 64 + ((kt * 32 + lq * 8) ^ swz)];
          acc1[rt][0] = MFMA(aw0, xb, acc1[rt][0]);
          acc1[rt][1] = MFMA(aw1, xb, acc1[rt][1]);
        }
      }
      #pragma unroll
      for (int kt = 0; kt < 8; ++kt) {   // recurrent, K=256
        s16x8 aw0 = *(const s16x8*)(Wp1h + ((size_t)(kt * 16 + 2 * wv) * 64 + lane) * 8);
        s16x8 aw1 = *(const s16x8*)(Wp1h + ((size_t)(kt * 16 + 2 * wv + 1) * 64 + lane) * 8);
        #pragma unroll
        for (int rt = 0; rt < 4; ++rt) {
          s16x8 hb = *(const s16x8*)&h1s[(rt * 16 + lr) * 256 + ((kt * 32 + lq * 8) ^ swz)];
          acc1[rt][0] = MFMA(aw0, hb, acc1[rt][0]);
          acc1[rt][1] = MFMA(aw1, hb, acc1[rt][1]);
        }
      }
      // epi: park tanh(acc1) in hscr - acc1 dies here
      #pragma unroll
      for (int j = 0; j < 2; ++j) {
        int cb = (2 * wv + j) * 16 + lq * 4;
        #pragma unroll
        for (int rt = 0; rt < 4; ++rt)
          *(s16x4*)&hscr[(rt * 16 + lr) * 256 + (cb ^ swz)] = tanh4bf(acc1[rt][j]);
      }
    }

    // ---------- Phase A2: cell 2 (acc2 = 32 VGPRs live)
    {
      f32x4 acc2[4][2];
      #pragma unroll
      for (int j = 0; j < 2; ++j) {
        int nb = (2 * wv + j) * 16 + lq * 4;
        f32x4 b2 = *(const f32x4*)(bh2v + nb);
        #pragma unroll
        for (int rt = 0; rt < 4; ++rt) acc2[rt][j] = b2;
      }
      #pragma unroll
      for (int kt = 0; kt < 2; ++kt) {   // x part, K=64 (from LDS)
        s16x8 aw0 = *(const s16x8*)(Wp2i + ((size_t)(kt * 16 + 2 * wv) * 64 + lane) * 8);
        s16x8 aw1 = *(const s16x8*)(Wp2i + ((size_t)(kt * 16 + 2 * wv + 1) * 64 + lane) * 8);
        #pragma unroll
        for (int rt = 0; rt < 4; ++rt) {
          s16x8 xb = *(const s16x8*)&xls[(rt * 16 + lr) * 64 + ((kt * 32 + lq * 8) ^ swz)];
          acc2[rt][0] = MFMA(aw0, xb, acc2[rt][0]);
          acc2[rt][1] = MFMA(aw1, xb, acc2[rt][1]);
        }
      }
      #pragma unroll
      for (int kt = 0; kt < 8; ++kt) {   // recurrent, K=256
        s16x8 aw0 = *(const s16x8*)(Wp2h + ((size_t)(kt * 16 + 2 * wv) * 64 + lane) * 8);
        s16x8 aw1 = *(const s16x8*)(Wp2h + ((size_t)(kt * 16 + 2 * wv + 1) * 64 + lane) * 8);
        #pragma unroll
        for (int rt = 0; rt < 4; ++rt) {
          s16x8 hb = *(const s16x8*)&h2s[(rt * 16 + lr) * 256 + ((kt * 32 + lq * 8) ^ swz)];
          acc2[rt][0] = MFMA(aw0, hb, acc2[rt][0]);
          acc2[rt][1] = MFMA(aw1, hb, acc2[rt][1]);
        }
      }
      __syncthreads();   // bar2: h2s/xls reads done, hscr fully written
      #pragma unroll
      for (int j = 0; j < 2; ++j) {
        int cb = (2 * wv + j) * 16 + lq * 4;
        #pragma unroll
        for (int rt = 0; rt < 4; ++rt)
          *(s16x4*)&h2s[(rt * 16 + lr) * 256 + (cb ^ swz)] = tanh4bf(acc2[rt][j]);
      }
      #pragma unroll
      for (int i = 0; i < 4; ++i) {
        int e = (i * 512 + tid) * 8;
        *(s16x8*)&h1s[e] = *(const s16x8*)&hscr[e];
      }
      __syncthreads();   // bar3: h1s/h2s ready
    }

    // ---------- Phase B+Crec: o-GEMM and h3-recurrent GEMM (independent streams)
    f32x4 acc3[4][2];
    {
      #pragma unroll
      for (int j = 0; j < 2; ++j) {
        int nb = (2 * wv + j) * 16 + lq * 4;
        f32x4 bb  = *(const f32x4*)(bh3v + nb);
        f32x4 c0w = *(const f32x4*)(w3c0 + nb);
        f32x4 c1w = *(const f32x4*)(w3c1 + nb);
        #pragma unroll
        for (int rt = 0; rt < 4; ++rt) {
          float cz = cue0[rt * 16 + lr], co = cue1[rt * 16 + lr];
          acc3[rt][j] = bb + cz * c0w + co * c1w;
        }
      }
      int cell = wv >> 2, w4 = wv & 3;
      const short* hs = cell ? h2s : h1s;
      const short* Wo = cell ? Wp2o : Wp1o;
      const float* bo = cell ? bo2v : bo1v;
      int nb = w4 * 16 + lq * 4;
      f32x4 bb = *(const f32x4*)(bo + nb);
      f32x4 acco[4];
      #pragma unroll
      for (int rt = 0; rt < 4; ++rt) acco[rt] = bb;
      // interleaved: h3-recurrent (old h3s, written only in C' after barrier)
      #pragma unroll
      for (int kt = 0; kt < 8; ++kt) {
        s16x8 aw0 = *(const s16x8*)(Wp3h + ((size_t)(kt * 16 + 2 * wv) * 64 + lane) * 8);
        s16x8 aw1 = *(const s16x8*)(Wp3h + ((size_t)(kt * 16 + 2 * wv + 1) * 64 + lane) * 8);
        s16x8 awo = *(const s16x8*)(Wo + ((size_t)(kt * 4 + w4) * 64 + lane) * 8);
        #pragma unroll
        for (int rt = 0; rt < 4; ++rt) {
          s16x8 hb3 = *(const s16x8*)&h3s[(rt * 16 + lr) * 256 + ((kt * 32 + lq * 8) ^ swz)];
          s16x8 hbo = *(const s16x8*)&hs[(rt * 16 + lr) * 256 + ((kt * 32 + lq * 8) ^ swz)];
          acc3[rt][0] = MFMA(aw0, hb3, acc3[rt][0]);
          acc3[rt][1] = MFMA(aw1, hb3, acc3[rt][1]);
          acco[rt] = MFMA(awo, hbo, acco[rt]);
        }
      }
      int cb = cell * 64 + nb;
      #pragma unroll
      for (int rt = 0; rt < 4; ++rt)
        *(s16x4*)&o12s[(rt * 16 + lr) * 128 + (cb ^ swz)] = tanh4bf(acco[rt]);
    }
    __syncthreads();   // bar4: o12s ready; all old-h3 reads complete

    // ---------- Phase C': ab-part (K=128) into acc3, then write h3new
    {
      #pragma unroll
      for (int kt = 0; kt < 4; ++kt) {
        s16x8 aw0 = *(const s16x8*)(Wp3ab + ((size_t)(kt * 16 + 2 * wv) * 64 + lane) * 8);
        s16x8 aw1 = *(const s16x8*)(Wp3ab + ((size_t)(kt * 16 + 2 * wv + 1) * 64 + lane) * 8);
        #pragma unroll
        for (int rt = 0; rt < 4; ++rt) {
          s16x8 ob = *(const s16x8*)&o12s[(rt * 16 + lr) * 128 + ((kt * 32 + lq * 8) ^ swz)];
          acc3[rt][0] = MFMA(aw0, ob, acc3[rt][0]);
          acc3[rt][1] = MFMA(aw1, ob, acc3[rt][1]);
        }
      }
      // write h3new directly: old-h3 readers all completed before bar4
      #pragma unroll
      for (int j = 0; j < 2; ++j) {
        int cb = (2 * wv + j) * 16 + lq * 4;
        #pragma unroll
        for (int rt = 0; rt < 4; ++rt)
          *(s16x4*)&h3s[(rt * 16 + lr) * 256 + (cb ^ swz)] = tanh4bf(acc3[rt][j]);
      }
    }
    __syncthreads();   // bar5: h3new ready

    // ---------- x(t+1) prefetch: issue loads now (latency hides under D/E)
    int tn = (t + 1 < TT) ? (t + 1) : t;
    const float* pxn = x + ((size_t)tn * BN + r0 + xr) * 64 + xcq;
    f32x4 xa0 = nt_ld4(pxn);
    f32x4 xa1 = nt_ld4(pxn + 4);

    // ---------- Phase D: waves 0-3 compute of; waves 4-7 store o1s/o2s (NT)
    if (wv < 4) {
      int nb = wv * 16 + lq * 4;
      f32x4 bb = *(const f32x4*)(bofv + nb);
      f32x4 acc[4];
      #pragma unroll
      for (int rt = 0; rt < 4; ++rt) acc[rt] = bb;
      #pragma unroll
      for (int kt = 0; kt < 8; ++kt) {
        s16x8 aw = *(const s16x8*)(Wp3o + ((size_t)(kt * 4 + wv) * 64 + lane) * 8);
        #pragma unroll
        for (int rt = 0; rt < 4; ++rt) {
          s16x8 hb = *(const s16x8*)&h3s[(rt * 16 + lr) * 256 + ((kt * 32 + lq * 8) ^ swz)];
          acc[rt] = MFMA(aw, hb, acc[rt]);
        }
      }
      #pragma unroll
      for (int rt = 0; rt < 4; ++rt) {
        f32x4 v = (f32x4){fmaxf(0.f, acc[rt][0]), fmaxf(0.f, acc[rt][1]),
                          fmaxf(0.f, acc[rt][2]), fmaxf(0.f, acc[rt][3])};
        *(f32x4*)&ofl[(rt * 16 + lr) * 72 + nb] = v;
      }
    } else {
      size_t ob = ((size_t)t * BN + r0) * 64;
      float* targ = (wv < 6) ? out_o1s : out_o2s;
      int coff = (wv < 6) ? 0 : 64;
      int wq = wv & 1;
      #pragma unroll
      for (int s = 0; s < 8; ++s) {
        int f = wq * 2048 + s * 256 + lane * 4;
        int r = f >> 6, c = f & 63;
        s16x4 v = *(const s16x4*)&o12s[r * 128 + ((c + coff) ^ ((r & 7) << 3))];
        nt_st4(targ + ob + f, (f32x4){bf2f(v[0]), bf2f(v[1]), bf2f(v[2]), bf2f(v[3])});
      }
    }
    BARL();   // D->E: ofl (LDS) hazard only; skip the NT-store drain

    // ---------- Phase E: of store + y + cue_arr + feed zero-fill (NT)
    //            + xls(t+1) write (fenced by loop-top BARL)
    {
      size_t ob = ((size_t)t * BN + r0) * 64;
      int r = tid >> 3, c0 = (tid & 7) << 3;
      nt_st4(out_of + ob + r * 64 + c0,     *(const f32x4*)&ofl[r * 72 + c0]);
      nt_st4(out_of + ob + r * 64 + c0 + 4, *(const f32x4*)&ofl[r * 72 + c0 + 4]);
      *(s16x8*)&xls[xr * 64 + (xcq ^ ((xr & 7) << 3))] =
          (s16x8){f2bf(xa0[0]), f2bf(xa0[1]), f2bf(xa0[2]), f2bf(xa0[3]),
                  f2bf(xa1[0]), f2bf(xa1[1]), f2bf(xa1[2]), f2bf(xa1[3])};
      if (tid < 128) {
        int rr = tid >> 1, jj = tid & 1;
        const f32x4* wr4 = (const f32x4*)(wfcv + jj * 64);
        const f32x4* or4 = (const f32x4*)&ofl[rr * 72];
        f32x4 sv = (f32x4){0.f, 0.f, 0.f, 0.f};
        #pragma unroll
        for (int kk = 0; kk < 16; ++kk) sv += or4[kk] * wr4[kk];
        float s = bfcv[jj] + sv[0] + sv[1] + sv[2] + sv[3];
        size_t yi = ((size_t)t * BN + r0 + rr) * 2 + jj;
        __builtin_nontemporal_store(s, out_ys + yi);
        __builtin_nontemporal_store(jj ? cue1[rr] : cue0[rr], out_cue + yi);
      }
      size_t fb = ((size_t)t * BN + r0) * 256;   // 16384 floats per feed array
      f32x4 z = (f32x4){0.f, 0.f, 0.f, 0.f};
      #pragma unroll
      for (int s = 0; s < 8; ++s) {
        nt_st4(out_f1 + fb + (size_t)(s * 512 + tid) * 4, z);
        nt_st4(out_f2 + fb + (size_t)(s * 512 + tid) * 4, z);
      }
    }
    // loop-top BARL() of step t+1 fences ofl-vs-hscr reuse and xls handoff
  }

  // final h states
  for (int i = tid; i < 4096; i += 512) {
    int r = i >> 6, c0 = (i & 63) << 2;
    int li = r * 256 + (c0 ^ ((r & 7) << 3));
    size_t g = (size_t)(r0 + r) * 256 + c0;
    s16x4 s1 = *(const s16x4*)&h1s[li];
    s16x4 s2 = *(const s16x4*)&h2s[li];
    s16x4 s3 = *(const s16x4*)&h3s[li];
    nt_st4(out_h1 + g, (f32x4){bf2f(s1[0]), bf2f(s1[1]), bf2f(s1[2]), bf2f(s1[3])});
    nt_st4(out_h2 + g, (f32x4){bf2f(s2[0]), bf2f(s2[1]), bf2f(s2[2]), bf2f(s2[3])});
    nt_st4(out_h3 + g, (f32x4){bf2f(s3[0]), bf2f(s3[1]), bf2f(s3[2]), bf2f(s3[3])});
  }
}

extern "C" void kernel_launch(void* const* d_in, const int* in_sizes, int n_in,
                              void* d_out, int out_size, void* d_ws, size_t ws_size,
                              hipStream_t stream) {
  const float* x   = (const float*)d_in[0];
  const float* cue = (const float*)d_in[1];
  const float* hc1 = (const float*)d_in[2];
  const float* hc2 = (const float*)d_in[3];
  const float* hc3 = (const float*)d_in[4];
  const float* hc4 = (const float*)d_in[5];
  PrepPtrs pp;
  pp.w1i = (const float*)d_in[6];  pp.b1i = (const float*)d_in[7];
  pp.w1h = (const float*)d_in[8];  pp.b1h = (const float*)d_in[9];
  pp.w1o = (const float*)d_in[10]; pp.bo1 = (const float*)d_in[11];
  pp.w2i = (const float*)d_in[12]; pp.b2i = (const float*)d_in[13];
  pp.w2h = (const float*)d_in[14]; pp.b2h = (const float*)d_in[15];
  pp.w2o = (const float*)d_in[16]; pp.bo2 = (const float*)d_in[17];
  pp.w3i = (const float*)d_in[18]; pp.b3i = (const float*)d_in[19];
  pp.w3h = (const float*)d_in[20]; pp.b3h = (const float*)d_in[21];
  pp.w3o = (const float*)d_in[22]; pp.bo3 = (const float*)d_in[23];
  pp.wfc = (const float*)d_in[24]; pp.bfc = (const float*)d_in[25];

  short* wpk   = (short*)d_ws;                       // 311296 bf16 = 622592 B
  float* wmisc = (float*)((char*)d_ws + 622592);     // 1602 f32

  prep_kernel<<<64, 256, 0, stream>>>(pp, wpk, wmisc);
  rnn_main<<<256, 512, 0, stream>>>(x, cue, hc1, hc2, hc3, hc4, wpk, wmisc, (float*)d_out);
}

// Round 16
// 513.970 us; speedup vs baseline: 1.2290x; 1.2290x over previous
//
#include <hip/hip_runtime.h>
#include <hip/hip_bf16.h>
#include <stdint.h>
#include <stddef.h>

// RNN_arch_2_final: 3-cell stacked RNN, T=16, B=16384, hidden 256.
// R16 = R14 structure EXACTLY (best: 524us; no cross-barrier accumulators -
// R15's B+Crec merge spilled and regressed) + the two VALU trims R15
// validated: f2bf via __float2bfloat16 cast, tanh = 1-2*rcp(e+1) upper-clamp.

#define BN 16384
#define TT 16

typedef short s16x8 __attribute__((ext_vector_type(8)));
typedef short s16x4 __attribute__((ext_vector_type(4)));
typedef float f32x4 __attribute__((ext_vector_type(4)));

#define MFMA(a, b, c) __builtin_amdgcn_mfma_f32_16x16x32_bf16((a), (b), (c), 0, 0, 0)
// LDS-ordering barrier WITHOUT vmcnt drain (loop-top, D->E only).
#define BARL() asm volatile("s_waitcnt lgkmcnt(0)\n\ts_barrier" ::: "memory")

__device__ __forceinline__ short f2bf(float f) {
  __hip_bfloat16 h = __float2bfloat16(f);
  short s;
  __builtin_memcpy(&s, &h, 2);
  return s;
}
__device__ __forceinline__ float bf2f(short s) {
  union { uint32_t u; float f; } v; v.u = ((uint32_t)(uint16_t)s) << 16;
  return v.f;
}
__device__ __forceinline__ float fast_tanh(float x) {
  float e = __expf(2.f * fminf(x, 8.f));   // exp(-big)->0 is benign: gives -1
  return 1.f - 2.f * __builtin_amdgcn_rcpf(e + 1.f);
}
__device__ __forceinline__ void nt_st4(float* p, f32x4 v) {
  __builtin_nontemporal_store(v, (f32x4*)p);
}
__device__ __forceinline__ f32x4 nt_ld4(const float* p) {
  return __builtin_nontemporal_load((const f32x4*)p);
}
__device__ __forceinline__ s16x4 tanh4bf(f32x4 a) {
  return (s16x4){f2bf(fast_tanh(a[0])), f2bf(fast_tanh(a[1])),
                 f2bf(fast_tanh(a[2])), f2bf(fast_tanh(a[3]))};
}

struct PrepPtrs {
  const float *w1i, *w1h, *w1o, *w2i, *w2h, *w2o, *w3i, *w3h, *w3o;
  const float *b1i, *b1h, *b2i, *b2h, *b3i, *b3h, *bo1, *bo2, *bo3, *wfc, *bfc;
};

// Pack W[n][k] fragments: frag(kt,nt): elem(lane,e) = W[nt*16+(lane&15)][kt*32+(lane>>4)*8+e]
__global__ void prep_kernel(PrepPtrs pp, short* __restrict__ wpk, float* __restrict__ wmisc) {
  const float* P[9] = {pp.w1i, pp.w1h, pp.w1o, pp.w2i, pp.w2h, pp.w2o, pp.w3i, pp.w3h, pp.w3o};
  const int LD_[9] = {64, 256, 256, 64, 256, 256, 130, 256, 256};
  const int C0_[9] = {0, 0, 0, 0, 0, 0, 2, 0, 0};
  const int NT_[9] = {16, 16, 4, 16, 16, 4, 16, 16, 4};
  const int DO_[10] = {0, 16384, 81920, 98304, 114688, 180224, 196608, 229376, 294912, 311296};
  int stride = gridDim.x * blockDim.x;
  for (int g = blockIdx.x * blockDim.x + threadIdx.x; g < 311296; g += stride) {
    int m = 0;
    while (g >= DO_[m + 1]) ++m;
    int p = g - DO_[m];
    int NT = NT_[m];
    int frag = p >> 9, lane = (p >> 3) & 63, e = p & 7;
    int kt = frag / NT, nt = frag - kt * NT;
    int row = nt * 16 + (lane & 15);
    int col = kt * 32 + ((lane >> 4) << 3) + e;
    wpk[g] = f2bf(P[m][(size_t)row * LD_[m] + C0_[m] + col]);
  }
  for (int i = blockIdx.x * blockDim.x + threadIdx.x; i < 1602; i += stride) {
    float v;
    if      (i < 256)  v = pp.b1i[i]         + pp.b1h[i];
    else if (i < 512)  v = pp.b2i[i - 256]   + pp.b2h[i - 256];
    else if (i < 768)  v = pp.b3i[i - 512]   + pp.b3h[i - 512];
    else if (i < 832)  v = pp.bo1[i - 768];
    else if (i < 896)  v = pp.bo2[i - 832];
    else if (i < 960)  v = pp.bo3[i - 896];
    else if (i < 1088) v = pp.wfc[i - 960];
    else if (i < 1090) v = pp.bfc[i - 1088];
    else if (i < 1346) v = pp.w3i[(size_t)(i - 1090) * 130];
    else               v = pp.w3i[(size_t)(i - 1346) * 130 + 1];
    wmisc[i] = v;
  }
}

__launch_bounds__(512, 2)
__global__ void rnn_main(const float* __restrict__ x, const float* __restrict__ cue,
                         const float* __restrict__ hc1, const float* __restrict__ hc2,
                         const float* __restrict__ hc3, const float* __restrict__ hc4,
                         const short* __restrict__ wpk, const float* __restrict__ wmisc,
                         float* __restrict__ out) {
  // LDS pool. h tiles: element (r,c) at [r*256 + (c ^ ((r&7)<<3))].
  // Union (o12s+ofl | hscr): hscr live A1-epi..A2-epi; loop-top BARL fences.
  __shared__ __align__(16) char pool[141312];
  short* h1s  = (short*)pool;                    // 32768 B
  short* h2s  = (short*)(pool + 32768);          // 32768 B
  short* h3s  = (short*)(pool + 65536);          // 32768 B
  short* o12s = (short*)(pool + 98304);          // 16384 B  (union w/ hscr)
  float* ofl  = (float*)(pool + 114688);         // 18432 B  (union w/ hscr tail)
  short* hscr = (short*)(pool + 98304);          // 32768 B  scratch for h1new
  short* xls  = (short*)(pool + 133120);         // 8192 B   x tile (bf16, swz)
  __shared__ float cue0[64], cue1[64];
  __shared__ __align__(16) float misc[1604];

  const int tid = threadIdx.x;
  const int wv = tid >> 6;          // 0..7
  const int lane = tid & 63;
  const int lr = lane & 15;
  const int lq = lane >> 4;
  const int swz = (lr & 7) << 3;
  const int r0 = blockIdx.x * 64;

  float* out_ys  = out;
  float* out_h1  = out + 524288;
  float* out_h2  = out + 4718592;
  float* out_h3  = out + 8912896;
  float* out_h4  = out + 13107200;
  float* out_o1s = out + 17301504;
  float* out_o2s = out + 34078720;
  float* out_cue = out + 50855936;
  float* out_f1  = out + 51380224;
  float* out_f2  = out + 118489088;
  float* out_of  = out + 185597952;

  for (int i = tid; i < 1602; i += 512) misc[i] = wmisc[i];
  if (tid < 64) {
    float cv = cue[r0 + tid];
    cue0[tid] = cv * 10.f;
    cue1[tid] = 10.f * fabsf(cv - 1.f);
  }
  // stage initial h (f32 -> bf16, swizzled) + h4 passthrough
  for (int i = tid; i < 4096; i += 512) {
    int r = i >> 6, c0 = (i & 63) << 2;
    int li = r * 256 + (c0 ^ ((r & 7) << 3));
    size_t g = (size_t)(r0 + r) * 256 + c0;
    f32x4 v1 = __builtin_nontemporal_load((const f32x4*)(hc1 + g));
    f32x4 v2 = __builtin_nontemporal_load((const f32x4*)(hc2 + g));
    f32x4 v3 = __builtin_nontemporal_load((const f32x4*)(hc3 + g));
    f32x4 v4 = __builtin_nontemporal_load((const f32x4*)(hc4 + g));
    *(s16x4*)&h1s[li] = (s16x4){f2bf(v1[0]), f2bf(v1[1]), f2bf(v1[2]), f2bf(v1[3])};
    *(s16x4*)&h2s[li] = (s16x4){f2bf(v2[0]), f2bf(v2[1]), f2bf(v2[2]), f2bf(v2[3])};
    *(s16x4*)&h3s[li] = (s16x4){f2bf(v3[0]), f2bf(v3[1]), f2bf(v3[2]), f2bf(v3[3])};
    nt_st4(out_h4 + g, v4);
  }
  // stage x(t=0) into xls (prologue)
  const int xr = tid >> 3, xcq = (tid & 7) << 3;
  {
    const float* px = x + ((size_t)(r0 + xr)) * 64 + xcq;
    f32x4 a0 = nt_ld4(px);
    f32x4 a1 = nt_ld4(px + 4);
    *(s16x8*)&xls[xr * 64 + (xcq ^ ((xr & 7) << 3))] =
        (s16x8){f2bf(a0[0]), f2bf(a0[1]), f2bf(a0[2]), f2bf(a0[3]),
                f2bf(a1[0]), f2bf(a1[1]), f2bf(a1[2]), f2bf(a1[3])};
  }
  __syncthreads();

  const short* Wp1i  = wpk;
  const short* Wp1h  = wpk + 16384;
  const short* Wp1o  = wpk + 81920;
  const short* Wp2i  = wpk + 98304;
  const short* Wp2h  = wpk + 114688;
  const short* Wp2o  = wpk + 180224;
  const short* Wp3ab = wpk + 196608;
  const short* Wp3h  = wpk + 229376;
  const short* Wp3o  = wpk + 294912;
  const float* bh1v = misc;
  const float* bh2v = misc + 256;
  const float* bh3v = misc + 512;
  const float* bo1v = misc + 768;
  const float* bo2v = misc + 832;
  const float* bofv = misc + 896;
  const float* wfcv = misc + 960;
  const float* bfcv = misc + 1088;
  const float* w3c0 = misc + 1090;
  const float* w3c1 = misc + 1346;

  for (int t = 0; t < TT; ++t) {
    BARL();   // loop-top: LDS-only hazard fence (E(t-1) vs A1 hscr / xls)

    // ---------- Phase A1: cell 1 only (acc1 = 32 VGPRs live)
    {
      f32x4 acc1[4][2];
      #pragma unroll
      for (int j = 0; j < 2; ++j) {
        int nb = (2 * wv + j) * 16 + lq * 4;
        f32x4 b1 = *(const f32x4*)(bh1v + nb);
        #pragma unroll
        for (int rt = 0; rt < 4; ++rt) acc1[rt][j] = b1;
      }
      #pragma unroll
      for (int kt = 0; kt < 2; ++kt) {   // x part, K=64 (from LDS)
        s16x8 aw0 = *(const s16x8*)(Wp1i + ((size_t)(kt * 16 + 2 * wv) * 64 + lane) * 8);
        s16x8 aw1 = *(const s16x8*)(Wp1i + ((size_t)(kt * 16 + 2 * wv + 1) * 64 + lane) * 8);
        #pragma unroll
        for (int rt = 0; rt < 4; ++rt) {
          s16x8 xb = *(const s16x8*)&xls[(rt * 16 + lr) * 64 + ((kt * 32 + lq * 8) ^ swz)];
          acc1[rt][0] = MFMA(aw0, xb, acc1[rt][0]);
          acc1[rt][1] = MFMA(aw1, xb, acc1[rt][1]);
        }
      }
      #pragma unroll
      for (int kt = 0; kt < 8; ++kt) {   // recurrent, K=256
        s16x8 aw0 = *(const s16x8*)(Wp1h + ((size_t)(kt * 16 + 2 * wv) * 64 + lane) * 8);
        s16x8 aw1 = *(const s16x8*)(Wp1h + ((size_t)(kt * 16 + 2 * wv + 1) * 64 + lane) * 8);
        #pragma unroll
        for (int rt = 0; rt < 4; ++rt) {
          s16x8 hb = *(const s16x8*)&h1s[(rt * 16 + lr) * 256 + ((kt * 32 + lq * 8) ^ swz)];
          acc1[rt][0] = MFMA(aw0, hb, acc1[rt][0]);
          acc1[rt][1] = MFMA(aw1, hb, acc1[rt][1]);
        }
      }
      // epi: park tanh(acc1) in hscr - acc1 dies here
      #pragma unroll
      for (int j = 0; j < 2; ++j) {
        int cb = (2 * wv + j) * 16 + lq * 4;
        #pragma unroll
        for (int rt = 0; rt < 4; ++rt)
          *(s16x4*)&hscr[(rt * 16 + lr) * 256 + (cb ^ swz)] = tanh4bf(acc1[rt][j]);
      }
    }

    // ---------- Phase A2: cell 2 (acc2 = 32 VGPRs live)
    {
      f32x4 acc2[4][2];
      #pragma unroll
      for (int j = 0; j < 2; ++j) {
        int nb = (2 * wv + j) * 16 + lq * 4;
        f32x4 b2 = *(const f32x4*)(bh2v + nb);
        #pragma unroll
        for (int rt = 0; rt < 4; ++rt) acc2[rt][j] = b2;
      }
      #pragma unroll
      for (int kt = 0; kt < 2; ++kt) {   // x part, K=64 (from LDS)
        s16x8 aw0 = *(const s16x8*)(Wp2i + ((size_t)(kt * 16 + 2 * wv) * 64 + lane) * 8);
        s16x8 aw1 = *(const s16x8*)(Wp2i + ((size_t)(kt * 16 + 2 * wv + 1) * 64 + lane) * 8);
        #pragma unroll
        for (int rt = 0; rt < 4; ++rt) {
          s16x8 xb = *(const s16x8*)&xls[(rt * 16 + lr) * 64 + ((kt * 32 + lq * 8) ^ swz)];
          acc2[rt][0] = MFMA(aw0, xb, acc2[rt][0]);
          acc2[rt][1] = MFMA(aw1, xb, acc2[rt][1]);
        }
      }
      #pragma unroll
      for (int kt = 0; kt < 8; ++kt) {   // recurrent, K=256
        s16x8 aw0 = *(const s16x8*)(Wp2h + ((size_t)(kt * 16 + 2 * wv) * 64 + lane) * 8);
        s16x8 aw1 = *(const s16x8*)(Wp2h + ((size_t)(kt * 16 + 2 * wv + 1) * 64 + lane) * 8);
        #pragma unroll
        for (int rt = 0; rt < 4; ++rt) {
          s16x8 hb = *(const s16x8*)&h2s[(rt * 16 + lr) * 256 + ((kt * 32 + lq * 8) ^ swz)];
          acc2[rt][0] = MFMA(aw0, hb, acc2[rt][0]);
          acc2[rt][1] = MFMA(aw1, hb, acc2[rt][1]);
        }
      }
      __syncthreads();   // bar2: h2s/xls reads done, hscr fully written
      #pragma unroll
      for (int j = 0; j < 2; ++j) {
        int cb = (2 * wv + j) * 16 + lq * 4;
        #pragma unroll
        for (int rt = 0; rt < 4; ++rt)
          *(s16x4*)&h2s[(rt * 16 + lr) * 256 + (cb ^ swz)] = tanh4bf(acc2[rt][j]);
      }
      #pragma unroll
      for (int i = 0; i < 4; ++i) {
        int e = (i * 512 + tid) * 8;
        *(s16x8*)&h1s[e] = *(const s16x8*)&hscr[e];
      }
      __syncthreads();   // bar3: h1s/h2s ready
    }

    // ---------- Phase B: o1 (waves 0-3) / o2 (waves 4-7)
    {
      int cell = wv >> 2, w4 = wv & 3;
      const short* hs = cell ? h2s : h1s;
      const short* Wo = cell ? Wp2o : Wp1o;
      const float* bo = cell ? bo2v : bo1v;
      int nb = w4 * 16 + lq * 4;
      f32x4 bb = *(const f32x4*)(bo + nb);
      f32x4 acc[4];
      #pragma unroll
      for (int rt = 0; rt < 4; ++rt) acc[rt] = bb;
      #pragma unroll
      for (int kt = 0; kt < 8; ++kt) {
        s16x8 aw = *(const s16x8*)(Wo + ((size_t)(kt * 4 + w4) * 64 + lane) * 8);
        #pragma unroll
        for (int rt = 0; rt < 4; ++rt) {
          s16x8 hb = *(const s16x8*)&hs[(rt * 16 + lr) * 256 + ((kt * 32 + lq * 8) ^ swz)];
          acc[rt] = MFMA(aw, hb, acc[rt]);
        }
      }
      int cb = cell * 64 + nb;
      #pragma unroll
      for (int rt = 0; rt < 4; ++rt)
        *(s16x4*)&o12s[(rt * 16 + lr) * 128 + (cb ^ swz)] = tanh4bf(acc[rt]);
    }
    __syncthreads();

    // ---------- Phase C: h3new
    {
      f32x4 acc3[4][2];
      #pragma unroll
      for (int j = 0; j < 2; ++j) {
        int nb = (2 * wv + j) * 16 + lq * 4;
        f32x4 bb  = *(const f32x4*)(bh3v + nb);
        f32x4 c0w = *(const f32x4*)(w3c0 + nb);
        f32x4 c1w = *(const f32x4*)(w3c1 + nb);
        #pragma unroll
        for (int rt = 0; rt < 4; ++rt) {
          float cz = cue0[rt * 16 + lr], co = cue1[rt * 16 + lr];
          acc3[rt][j] = bb + cz * c0w + co * c1w;
        }
      }
      #pragma unroll
      for (int kt = 0; kt < 4; ++kt) {   // [o1|o2], K=128
        s16x8 aw0 = *(const s16x8*)(Wp3ab + ((size_t)(kt * 16 + 2 * wv) * 64 + lane) * 8);
        s16x8 aw1 = *(const s16x8*)(Wp3ab + ((size_t)(kt * 16 + 2 * wv + 1) * 64 + lane) * 8);
        #pragma unroll
        for (int rt = 0; rt < 4; ++rt) {
          s16x8 ob = *(const s16x8*)&o12s[(rt * 16 + lr) * 128 + ((kt * 32 + lq * 8) ^ swz)];
          acc3[rt][0] = MFMA(aw0, ob, acc3[rt][0]);
          acc3[rt][1] = MFMA(aw1, ob, acc3[rt][1]);
        }
      }
      #pragma unroll
      for (int kt = 0; kt < 8; ++kt) {   // recurrent, K=256
        s16x8 aw0 = *(const s16x8*)(Wp3h + ((size_t)(kt * 16 + 2 * wv) * 64 + lane) * 8);
        s16x8 aw1 = *(const s16x8*)(Wp3h + ((size_t)(kt * 16 + 2 * wv + 1) * 64 + lane) * 8);
        #pragma unroll
        for (int rt = 0; rt < 4; ++rt) {
          s16x8 hb = *(const s16x8*)&h3s[(rt * 16 + lr) * 256 + ((kt * 32 + lq * 8) ^ swz)];
          acc3[rt][0] = MFMA(aw0, hb, acc3[rt][0]);
          acc3[rt][1] = MFMA(aw1, hb, acc3[rt][1]);
        }
      }
      __syncthreads();   // done reading old h3
      #pragma unroll
      for (int j = 0; j < 2; ++j) {
        int cb = (2 * wv + j) * 16 + lq * 4;
        #pragma unroll
        for (int rt = 0; rt < 4; ++rt)
          *(s16x4*)&h3s[(rt * 16 + lr) * 256 + (cb ^ swz)] = tanh4bf(acc3[rt][j]);
      }
      __syncthreads();
    }

    // ---------- x(t+1) prefetch: issue loads now (latency hides under D/E)
    int tn = (t + 1 < TT) ? (t + 1) : t;
    const float* pxn = x + ((size_t)tn * BN + r0 + xr) * 64 + xcq;
    f32x4 xa0 = nt_ld4(pxn);
    f32x4 xa1 = nt_ld4(pxn + 4);

    // ---------- Phase D: waves 0-3 compute of; waves 4-7 store o1s/o2s (NT)
    if (wv < 4) {
      int nb = wv * 16 + lq * 4;
      f32x4 bb = *(const f32x4*)(bofv + nb);
      f32x4 acc[4];
      #pragma unroll
      for (int rt = 0; rt < 4; ++rt) acc[rt] = bb;
      #pragma unroll
      for (int kt = 0; kt < 8; ++kt) {
        s16x8 aw = *(const s16x8*)(Wp3o + ((size_t)(kt * 4 + wv) * 64 + lane) * 8);
        #pragma unroll
        for (int rt = 0; rt < 4; ++rt) {
          s16x8 hb = *(const s16x8*)&h3s[(rt * 16 + lr) * 256 + ((kt * 32 + lq * 8) ^ swz)];
          acc[rt] = MFMA(aw, hb, acc[rt]);
        }
      }
      #pragma unroll
      for (int rt = 0; rt < 4; ++rt) {
        f32x4 v = (f32x4){fmaxf(0.f, acc[rt][0]), fmaxf(0.f, acc[rt][1]),
                          fmaxf(0.f, acc[rt][2]), fmaxf(0.f, acc[rt][3])};
        *(f32x4*)&ofl[(rt * 16 + lr) * 72 + nb] = v;
      }
    } else {
      size_t ob = ((size_t)t * BN + r0) * 64;
      float* targ = (wv < 6) ? out_o1s : out_o2s;
      int coff = (wv < 6) ? 0 : 64;
      int wq = wv & 1;
      #pragma unroll
      for (int s = 0; s < 8; ++s) {
        int f = wq * 2048 + s * 256 + lane * 4;
        int r = f >> 6, c = f & 63;
        s16x4 v = *(const s16x4*)&o12s[r * 128 + ((c + coff) ^ ((r & 7) << 3))];
        nt_st4(targ + ob + f, (f32x4){bf2f(v[0]), bf2f(v[1]), bf2f(v[2]), bf2f(v[3])});
      }
    }
    BARL();   // D->E: ofl (LDS) hazard only; skip the NT-store drain

    // ---------- Phase E: of store + y + cue_arr + feed zero-fill (NT)
    //            + xls(t+1) write (fenced by loop-top BARL)
    {
      size_t ob = ((size_t)t * BN + r0) * 64;
      int r = tid >> 3, c0 = (tid & 7) << 3;
      nt_st4(out_of + ob + r * 64 + c0,     *(const f32x4*)&ofl[r * 72 + c0]);
      nt_st4(out_of + ob + r * 64 + c0 + 4, *(const f32x4*)&ofl[r * 72 + c0 + 4]);
      *(s16x8*)&xls[xr * 64 + (xcq ^ ((xr & 7) << 3))] =
          (s16x8){f2bf(xa0[0]), f2bf(xa0[1]), f2bf(xa0[2]), f2bf(xa0[3]),
                  f2bf(xa1[0]), f2bf(xa1[1]), f2bf(xa1[2]), f2bf(xa1[3])};
      if (tid < 128) {
        int rr = tid >> 1, jj = tid & 1;
        const f32x4* wr4 = (const f32x4*)(wfcv + jj * 64);
        const f32x4* or4 = (const f32x4*)&ofl[rr * 72];
        f32x4 sv = (f32x4){0.f, 0.f, 0.f, 0.f};
        #pragma unroll
        for (int kk = 0; kk < 16; ++kk) sv += or4[kk] * wr4[kk];
        float s = bfcv[jj] + sv[0] + sv[1] + sv[2] + sv[3];
        size_t yi = ((size_t)t * BN + r0 + rr) * 2 + jj;
        __builtin_nontemporal_store(s, out_ys + yi);
        __builtin_nontemporal_store(jj ? cue1[rr] : cue0[rr], out_cue + yi);
      }
      size_t fb = ((size_t)t * BN + r0) * 256;   // 16384 floats per feed array
      f32x4 z = (f32x4){0.f, 0.f, 0.f, 0.f};
      #pragma unroll
      for (int s = 0; s < 8; ++s) {
        nt_st4(out_f1 + fb + (size_t)(s * 512 + tid) * 4, z);
        nt_st4(out_f2 + fb + (size_t)(s * 512 + tid) * 4, z);
      }
    }
    // loop-top BARL() of step t+1 fences ofl-vs-hscr reuse and xls handoff
  }

  // final h states
  for (int i = tid; i < 4096; i += 512) {
    int r = i >> 6, c0 = (i & 63) << 2;
    int li = r * 256 + (c0 ^ ((r & 7) << 3));
    size_t g = (size_t)(r0 + r) * 256 + c0;
    s16x4 s1 = *(const s16x4*)&h1s[li];
    s16x4 s2 = *(const s16x4*)&h2s[li];
    s16x4 s3 = *(const s16x4*)&h3s[li];
    nt_st4(out_h1 + g, (f32x4){bf2f(s1[0]), bf2f(s1[1]), bf2f(s1[2]), bf2f(s1[3])});
    nt_st4(out_h2 + g, (f32x4){bf2f(s2[0]), bf2f(s2[1]), bf2f(s2[2]), bf2f(s2[3])});
    nt_st4(out_h3 + g, (f32x4){bf2f(s3[0]), bf2f(s3[1]), bf2f(s3[2]), bf2f(s3[3])});
  }
}

extern "C" void kernel_launch(void* const* d_in, const int* in_sizes, int n_in,
                              void* d_out, int out_size, void* d_ws, size_t ws_size,
                              hipStream_t stream) {
  const float* x   = (const float*)d_in[0];
  const float* cue = (const float*)d_in[1];
  const float* hc1 = (const float*)d_in[2];
  const float* hc2 = (const float*)d_in[3];
  const float* hc3 = (const float*)d_in[4];
  const float* hc4 = (const float*)d_in[5];
  PrepPtrs pp;
  pp.w1i = (const float*)d_in[6];  pp.b1i = (const float*)d_in[7];
  pp.w1h = (const float*)d_in[8];  pp.b1h = (const float*)d_in[9];
  pp.w1o = (const float*)d_in[10]; pp.bo1 = (const float*)d_in[11];
  pp.w2i = (const float*)d_in[12]; pp.b2i = (const float*)d_in[13];
  pp.w2h = (const float*)d_in[14]; pp.b2h = (const float*)d_in[15];
  pp.w2o = (const float*)d_in[16]; pp.bo2 = (const float*)d_in[17];
  pp.w3i = (const float*)d_in[18]; pp.b3i = (const float*)d_in[19];
  pp.w3h = (const float*)d_in[20]; pp.b3h = (const float*)d_in[21];
  pp.w3o = (const float*)d_in[22]; pp.bo3 = (const float*)d_in[23];
  pp.wfc = (const float*)d_in[24]; pp.bfc = (const float*)d_in[25];

  short* wpk   = (short*)d_ws;                       // 311296 bf16 = 622592 B
  float* wmisc = (float*)((char*)d_ws + 622592);     // 1602 f32

  prep_kernel<<<64, 256, 0, stream>>>(pp, wpk, wmisc);
  rnn_main<<<256, 512, 0, stream>>>(x, cue, hc1, hc2, hc3, hc4, wpk, wmisc, (float*)d_out);
}